// Round 18
// baseline (137.146 us; speedup 1.0000x reference)
//
#include <hip/hip_runtime.h>
#include <hip/hip_bf16.h>

// PSAttentionBlock: B=16, C=KF=VF=128, H=W=128.
// out[b,f,h,w] = (v_w·x + v_b)[b,f,h,w] * S[b,h,w]
//   S[b,h,g] = sum_f softmax_{g<=h}( exp(Q[b,f]K[b,f]^T/sqrt(128)) )
//   Q/K from 1x1 conv with Weff[o,c] = qk_w[o,c]+qk_w[o,c+128]
// QK intermediate FP8 e4m3. K1: f-split 256-thr/4-wave blocks (grid z = Q/K
// half), 4 independent blocks/CU, 2-half inner loop, fp8 restage -> coalesced
// stores, lgkm-only barrier. K2: partial-S plain stores. K3: reduce+scale.

using short8 = __attribute__((ext_vector_type(8))) short;
using f32x4  = __attribute__((ext_vector_type(4))) float;
typedef unsigned short u16;
typedef unsigned int   u32;
typedef unsigned char  u8;

#define NB 16
#define NC 128
#define NP 16384
#define TILES_QK 4
#define TILES_V 8
#define NFG 16                       // fgroups in K2 (8 planes each)
#define SCALE 0.08838834764831845f   // 128^-0.5

__device__ inline u16 f2bf(float f) {
  u32 u = __float_as_uint(f);
  return (u16)((u + 0x7FFFu + ((u >> 16) & 1u)) >> 16);   // RNE
}
__device__ inline u32 pk2(float a, float b) {             // 2xf32 -> packed bf16x2
  union { __hip_bfloat162 h; u32 u; } cv;
  cv.h = __float22bfloat162_rn(make_float2(a, b));
  return cv.u;
}
__device__ inline f32x4 fz4(){ f32x4 z; z[0]=0.f; z[1]=0.f; z[2]=0.f; z[3]=0.f; return z; }
__device__ inline long u2l(uint2 v){ union{uint2 u; long l;} c; c.u = v; return c.l; }
// row-swizzle for bf16 x-tiles: XOR 16B-chunk index within a 256B row
__device__ inline int kap(int r){ return ((r ^ (r >> 2)) & 15) << 4; }

// barrier that drains ONLY LDS (lgkm) — global loads/stores keep flying.
__device__ inline void barrier_lgkm() {
  __builtin_amdgcn_sched_barrier(0);
  asm volatile("s_waitcnt lgkmcnt(0)" ::: "memory");
  __builtin_amdgcn_s_barrier();
  __builtin_amdgcn_sched_barrier(0);
}

// ---------------- K0: weight prep -> bf16 ----------------
__global__ __launch_bounds__(256) void prep_w(
    const float* __restrict__ qk_w, const float* __restrict__ v_w,
    u16* __restrict__ Weff, u16* __restrict__ Vw) {
  const int i = blockIdx.x * 256 + threadIdx.x;           // 16384 threads
  #pragma unroll
  for (int r = 0; r < 2; ++r) {
    const int e = i * 2 + r;
    const int f = e >> 7, c = e & 127;
    Weff[e] = f2bf(qk_w[f * 256 + c] + qk_w[f * 256 + 128 + c]);
  }
  Vw[i] = f2bf(v_w[i]);
}

// ---- 512-thread staging helpers (K3): [64 p][128 c] -> LDS transposed ----
__device__ inline void stage_issue(const float* __restrict__ xb, int tid,
                                   float4& r0, float4& r1, float4& r2, float4& r3) {
  const int c0 = (tid >> 4) * 4, p0 = (tid & 15) * 4;
  r0 = *(const float4*)(xb + (size_t)(c0 + 0) * NP + p0);
  r1 = *(const float4*)(xb + (size_t)(c0 + 1) * NP + p0);
  r2 = *(const float4*)(xb + (size_t)(c0 + 2) * NP + p0);
  r3 = *(const float4*)(xb + (size_t)(c0 + 3) * NP + p0);
}
__device__ inline void stage_write(u16* xs, int tid,
                                   float4 r0, float4 r1, float4 r2, float4 r3) {
  const int c0 = (tid >> 4) * 4, p0 = (tid & 15) * 4;
  const float* a0 = (const float*)&r0;
  const float* a1 = (const float*)&r1;
  const float* a2 = (const float*)&r2;
  const float* a3 = (const float*)&r3;
  #pragma unroll
  for (int j = 0; j < 4; ++j) {
    const int p = p0 + j;
    uint2 pk;
    pk.x = pk2(a0[j], a1[j]);
    pk.y = pk2(a2[j], a3[j]);
    *(uint2*)((char*)xs + p * 256 + ((c0 * 2) ^ kap(p))) = pk;
  }
}

// ---- 256-thread staging helpers (K1): [64 p][128 c] -> LDS transposed ----
__device__ inline void stage_issue256(const float* __restrict__ xb, int tid,
                                      float4& s0, float4& s1, float4& s2, float4& s3,
                                      float4& s4, float4& s5, float4& s6, float4& s7) {
  const int c0 = (tid >> 4) * 4, p0 = (tid & 15) * 4;
  s0 = *(const float4*)(xb + (size_t)(c0 + 0) * NP + p0);
  s1 = *(const float4*)(xb + (size_t)(c0 + 1) * NP + p0);
  s2 = *(const float4*)(xb + (size_t)(c0 + 2) * NP + p0);
  s3 = *(const float4*)(xb + (size_t)(c0 + 3) * NP + p0);
  s4 = *(const float4*)(xb + (size_t)(c0 + 64) * NP + p0);
  s5 = *(const float4*)(xb + (size_t)(c0 + 65) * NP + p0);
  s6 = *(const float4*)(xb + (size_t)(c0 + 66) * NP + p0);
  s7 = *(const float4*)(xb + (size_t)(c0 + 67) * NP + p0);
}
__device__ inline void stage_write256(u16* xs, int tid,
                                      float4 s0, float4 s1, float4 s2, float4 s3,
                                      float4 s4, float4 s5, float4 s6, float4 s7) {
  const int c0 = (tid >> 4) * 4, p0 = (tid & 15) * 4;
  const float* a0 = (const float*)&s0;
  const float* a1 = (const float*)&s1;
  const float* a2 = (const float*)&s2;
  const float* a3 = (const float*)&s3;
  const float* a4 = (const float*)&s4;
  const float* a5 = (const float*)&s5;
  const float* a6 = (const float*)&s6;
  const float* a7 = (const float*)&s7;
  #pragma unroll
  for (int j = 0; j < 4; ++j) {
    const int p = p0 + j;
    uint2 pk0, pk1;
    pk0.x = pk2(a0[j], a1[j]);
    pk0.y = pk2(a2[j], a3[j]);
    pk1.x = pk2(a4[j], a5[j]);
    pk1.y = pk2(a6[j], a7[j]);
    char* row = (char*)xs + p * 256;
    *(uint2*)(row + ((c0 * 2) ^ kap(p))) = pk0;
    *(uint2*)(row + (((c0 + 64) * 2) ^ kap(p))) = pk1;
  }
}

// ---------------- K1: QK conv -> fp8 planes, f-split 4-wave blocks -----------
// grid (64 tilegroups of 4x64p, 16 b, 2 f-halves), 256 thr;
// wave wv owns f = half*128 + [wv*32, wv*32+32).
__global__ __launch_bounds__(256, 2) void qk_conv(
    const float* __restrict__ x, const u16* __restrict__ Weff,
    const float* __restrict__ qk_b, u8* __restrict__ QK) {
  __shared__ u16 xs[2][64 * 128];             // 2 x 16 KB
  __shared__ char rb[4][2048];                // 4 waves x 2 KB fp8 restage
  const int b = blockIdx.y, tg = blockIdx.x, half = blockIdx.z, tid = threadIdx.x;
  const int wv = tid >> 6, l = tid & 63, l15 = l & 15, lq = l >> 4;
  const int fw = half * 128 + wv * 32;        // this wave's 32-f base
  const float* xb = x + (size_t)b * NC * NP + tg * (64 * TILES_QK);

  short8 wf[4][2];                             // tile-invariant, L2-resident
  #pragma unroll
  for (int ks = 0; ks < 4; ++ks) {
    const int cc = ks * 32 + lq * 8;
    wf[ks][0] = *(const short8*)(Weff + (size_t)(fw + l15) * 128 + cc);
    wf[ks][1] = *(const short8*)(Weff + (size_t)(fw + 16 + l15) * 128 + cc);
  }
  const float bias0 = qk_b[fw + l15];
  const float bias1 = qk_b[fw + 16 + l15];

  float4 s0, s1, s2, s3, s4, s5, s6, s7;
  stage_issue256(xb, tid, s0, s1, s2, s3, s4, s5, s6, s7);
  stage_write256(xs[0], tid, s0, s1, s2, s3, s4, s5, s6, s7);

  for (int t = 0; t < TILES_QK; ++t) {
    if (t + 1 < TILES_QK)
      stage_issue256(xb + (t + 1) * 64, tid, s0, s1, s2, s3, s4, s5, s6, s7);
    barrier_lgkm();

    const u16* cur = xs[t & 1];
    f32x4 acc[4][2];
    #pragma unroll
    for (int m = 0; m < 4; ++m) { acc[m][0] = fz4(); acc[m][1] = fz4(); }
    #pragma unroll
    for (int ks = 0; ks < 4; ++ks) {
      const int cc2 = (ks * 32 + lq * 8) * 2;
      #pragma unroll
      for (int m = 0; m < 4; ++m) {
        const int p = m * 16 + l15;
        short8 af = *(const short8*)((const char*)cur + p * 256 + (cc2 ^ kap(p)));
        acc[m][0] = __builtin_amdgcn_mfma_f32_16x16x32_bf16(af, wf[ks][0], acc[m][0], 0, 0, 0);
        acc[m][1] = __builtin_amdgcn_mfma_f32_16x16x32_bf16(af, wf[ks][1], acc[m][1], 0, 0, 0);
      }
    }

    if (t + 1 < TILES_QK)
      stage_write256(xs[(t + 1) & 1], tid, s0, s1, s2, s3, s4, s5, s6, s7);

    // pack fp8 (RNE) into per-wave restage LDS ([32 f][64 p] fp8, 16B-granule
    // XOR by f&3), then 2 coalesced 16B stores (16 planes x 64B per op).
    const int pbase = tg * (64 * TILES_QK) + t * 64;
    char* rbw = rb[wv];
    #pragma unroll
    for (int n = 0; n < 2; ++n) {
      const int fl = n * 16 + l15;
      const float bias = n ? bias1 : bias0;
      #pragma unroll
      for (int m = 0; m < 4; ++m) {
        int pk4 = __builtin_amdgcn_cvt_pk_fp8_f32(acc[m][n][0] + bias,
                                                  acc[m][n][1] + bias, 0, false);
        pk4 = __builtin_amdgcn_cvt_pk_fp8_f32(acc[m][n][2] + bias,
                                              acc[m][n][3] + bias, pk4, true);
        *(int*)(rbw + fl * 64 + ((m ^ (fl & 3)) * 16) + lq * 4) = pk4;
      }
    }
    #pragma unroll
    for (int i = 0; i < 2; ++i) {
      const int r = i * 16 + (l >> 2);
      const int pg = l & 3, lg = pg ^ (r & 3);      // physical/logical granule
      uint4 v = *(const uint4*)(rbw + r * 64 + pg * 16);
      *(uint4*)((char*)QK + (((size_t)(b * 256 + fw + r)) << 14)
                + pbase + lg * 16) = v;
    }
  }
}

// ---------------- K2: fp8 scores + causal softmax -> Spart[fg][b] ------------
// grid (16 fgroups of 8, 16 b), 512 thr; wave wv owns rows h [wv*16, wv*16+16)
// Plain stores of the per-fgroup partial S (full coverage -> no init needed).
__global__ __launch_bounds__(512, 2) void scores_softmax(
    const u8* __restrict__ QK, float* __restrict__ Spart) {
  __shared__ u8 Ksm[2][16384];                // 2 x 16 KB fp8 K planes
  const int b = blockIdx.y, fg = blockIdx.x, tid = threadIdx.x;
  const int wv = tid >> 6, l = tid & 63, l15 = l & 15, lq = l >> 4;
  const int hbase = wv * 16;

  // staging: dest 16B-granule linear, src granule XOR'd by ((row>>1)&7) within
  // its 128B row -> LDS content lands pre-swizzled (same cache lines -> free)
  int srcoff[2];
  #pragma unroll
  for (int s = 0; s < 2; ++s) {
    const int a = s * 512 + tid;              // granule 0..1023
    const int g = a >> 3, gr = a & 7;         // row, granule-in-row
    srcoff[s] = ((a & ~7) | (gr ^ ((g >> 1) & 7))) * 16;
  }

  {
    const char* kp = (const char*)QK + (((size_t)(b * 256 + 128 + fg * 8)) << 14);
    #pragma unroll
    for (int s = 0; s < 2; ++s)
      *(uint4*)((char*)Ksm[0] + (s * 512 + tid) * 16) = *(const uint4*)(kp + srcoff[s]);
  }
  __syncthreads();

  float Sacc[8][4];
  #pragma unroll
  for (int n = 0; n < 8; ++n)
    #pragma unroll
    for (int r = 0; r < 4; ++r) Sacc[n][r] = 0.f;

  for (int fi = 0; fi < 8; ++fi) {
    const u8* kb = Ksm[fi & 1];
    const bool pf = (fi < 7);
    uint4 st0, st1;
    if (pf) {
      const char* kp = (const char*)QK + (((size_t)(b * 256 + 128 + fg * 8 + fi + 1)) << 14);
      st0 = *(const uint4*)(kp + srcoff[0]);
      st1 = *(const uint4*)(kp + srcoff[1]);
    }

    const char* Qp = (const char*)QK + (((size_t)(b * 256 + fg * 8 + fi)) << 14);
    f32x4 acc[8];
    #pragma unroll
    for (int n = 0; n < 8; ++n) acc[n] = fz4();
    #pragma unroll
    for (int ks = 0; ks < 4; ++ks) {
      const int hq = hbase + l15;
      uint2 aq = *(const uint2*)(Qp + hq * 128 + ks * 32 + lq * 8);  // linear Q
      const long a8 = u2l(aq);
      #pragma unroll
      for (int n = 0; n < 8; ++n) {
        const int g = n * 16 + l15;
        uint2 bq = *(const uint2*)((const char*)kb + g * 128
                                   + (((ks * 4 + lq) ^ (g & 14)) << 3));
        acc[n] = __builtin_amdgcn_mfma_f32_16x16x32_fp8_fp8(a8, u2l(bq), acc[n], 0, 0, 0);
      }
    }

    float part[4] = {0.f, 0.f, 0.f, 0.f};
    #pragma unroll
    for (int n = 0; n < 8; ++n)
      #pragma unroll
      for (int r = 0; r < 4; ++r) {
        const int h = hbase + lq * 4 + r;
        const int g = n * 16 + l15;
        float e = (g <= h) ? __expf(acc[n][r] * SCALE) : 0.f;   // faithful: no max-sub
        acc[n][r] = e;
        part[r] += e;
      }
    #pragma unroll
    for (int r = 0; r < 4; ++r) {
      part[r] += __shfl_xor(part[r], 1);
      part[r] += __shfl_xor(part[r], 2);
      part[r] += __shfl_xor(part[r], 4);
      part[r] += __shfl_xor(part[r], 8);
    }
    #pragma unroll
    for (int r = 0; r < 4; ++r) part[r] = 1.0f / part[r];
    #pragma unroll
    for (int n = 0; n < 8; ++n)
      #pragma unroll
      for (int r = 0; r < 4; ++r) Sacc[n][r] += acc[n][r] * part[r];

    if (pf) {
      char* kd = (char*)Ksm[(fi & 1) ^ 1];
      *(uint4*)(kd + (0 * 512 + tid) * 16) = st0;
      *(uint4*)(kd + (1 * 512 + tid) * 16) = st1;
    }
    __syncthreads();
  }

  // plain stores: this block covers ALL 16384 (h,g) of its partial plane
  float* Sp = Spart + ((size_t)(fg * NB + b)) * NP;
  #pragma unroll
  for (int n = 0; n < 8; ++n)
    #pragma unroll
    for (int r = 0; r < 4; ++r) {
      const int h = hbase + lq * 4 + r, g = n * 16 + l15;
      Sp[h * 128 + g] = Sacc[n][r];
    }
}

// ---------------- K3: V conv + S-partial reduce + scale -> out ---------------
__device__ inline void v_compute(const u16* cur, int l15, int lq,
                                 f32x4 acc[4], const short8 wf[4]) {
  #pragma unroll
  for (int m = 0; m < 4; ++m) acc[m] = fz4();
  #pragma unroll
  for (int ks = 0; ks < 4; ++ks) {
    const int cc2 = (ks * 32 + lq * 8) * 2;
    #pragma unroll
    for (int m = 0; m < 4; ++m) {
      const int p = m * 16 + l15;
      short8 af = *(const short8*)((const char*)cur + p * 256 + (cc2 ^ kap(p)));
      acc[m] = __builtin_amdgcn_mfma_f32_16x16x32_bf16(af, wf[ks], acc[m], 0, 0, 0);
    }
  }
}
__device__ inline void v_store(float* orow, const float* Ssm, int lq,
                               const f32x4 acc[4], int pbase, int ploc, float vb) {
  #pragma unroll
  for (int m = 0; m < 4; ++m) {
    const int o = m * 16 + lq * 4;
    float4 sv = *(const float4*)(Ssm + ploc + o);
    float4 oo;
    oo.x = (acc[m][0] + vb) * sv.x;
    oo.y = (acc[m][1] + vb) * sv.y;
    oo.z = (acc[m][2] + vb) * sv.z;
    oo.w = (acc[m][3] + vb) * sv.w;
    *(float4*)(orow + pbase + o) = oo;
  }
}

// grid (32 tilegroups, 16 b), 512 thr; wave wv owns f [wv*16, wv*16+16)
__global__ __launch_bounds__(512, 2) void v_conv_mul(
    const float* __restrict__ x, const u16* __restrict__ Vw,
    const float* __restrict__ v_b, const float* __restrict__ Spart,
    float* __restrict__ out) {
  __shared__ u16 xs[2][64 * 128];
  __shared__ float Ssm[512];                  // reduced S for this block's 512 p
  const int b = blockIdx.y, tg = blockIdx.x, tid = threadIdx.x;
  const int wv = tid >> 6, l = tid & 63, l15 = l & 15, lq = l >> 4;
  const float* xb = x + (size_t)b * NC * NP + tg * (64 * TILES_V);

  short8 wf[4];
  #pragma unroll
  for (int ks = 0; ks < 4; ++ks)
    wf[ks] = *(const short8*)(Vw + (size_t)(wv * 16 + l15) * 128 + ks * 32 + lq * 8);
  const int f = wv * 16 + l15;
  const float vb = v_b[f];
  float* orow = out + (size_t)(b * 128 + f) * NP;

  // prologue: reduce 16 S partials for this block's p range into LDS
  {
    const size_t poff = (size_t)b * NP + tg * 512 + tid;
    float s = 0.f;
    #pragma unroll
    for (int q = 0; q < NFG; ++q) s += Spart[(size_t)q * NB * NP + poff];
    Ssm[tid] = s;
  }

  float4 A0, A1, A2, A3, B0, B1, B2, B3;
  stage_issue(xb, tid, A0, A1, A2, A3);
  stage_write(xs[0], tid, A0, A1, A2, A3);
  stage_issue(xb + 64, tid, B0, B1, B2, B3);

  f32x4 acc[4];
  #pragma unroll
  for (int tp = 0; tp < TILES_V; tp += 2) {
    barrier_lgkm();
    if (tp + 2 < TILES_V) stage_issue(xb + (tp + 2) * 64, tid, A0, A1, A2, A3);
    v_compute(xs[0], l15, lq, acc, wf);
    if (tp + 1 < TILES_V) stage_write(xs[1], tid, B0, B1, B2, B3);
    v_store(orow, Ssm, lq, acc, tg * (64 * TILES_V) + tp * 64, tp * 64, vb);
    barrier_lgkm();
    if (tp + 3 < TILES_V) stage_issue(xb + (tp + 3) * 64, tid, B0, B1, B2, B3);
    v_compute(xs[1], l15, lq, acc, wf);
    if (tp + 2 < TILES_V) stage_write(xs[0], tid, A0, A1, A2, A3);
    v_store(orow, Ssm, lq, acc, tg * (64 * TILES_V) + (tp + 1) * 64, (tp + 1) * 64, vb);
  }
}

extern "C" void kernel_launch(void* const* d_in, const int* in_sizes, int n_in,
                              void* d_out, int out_size, void* d_ws, size_t ws_size,
                              hipStream_t stream) {
  const float* x    = (const float*)d_in[0];
  const float* qk_w = (const float*)d_in[1];
  const float* qk_b = (const float*)d_in[2];
  const float* v_w  = (const float*)d_in[3];
  const float* v_b  = (const float*)d_in[4];
  float* out = (float*)d_out;

  char* ws = (char*)d_ws;
  u8*    QK    = (u8*)ws;                                  // 67,108,864 B (fp8)
  float* Spart = (float*)(ws + (size_t)67108864);          // 16,777,216 B
  u16*   Weff  = (u16*)(ws + (size_t)67108864 + 16777216); //     65,536 B
  u16*   Vw    = (u16*)(ws + (size_t)67108864 + 16777216 + 65536);  // 32,768 B

  prep_w<<<64, 256, 0, stream>>>(qk_w, v_w, Weff, Vw);
  qk_conv<<<dim3(64, 16, 2), 256, 0, stream>>>(x, Weff, qk_b, QK);
  scores_softmax<<<dim3(16, 16), 512, 0, stream>>>(QK, Spart);
  v_conv_mul<<<dim3(32, 16), 512, 0, stream>>>(x, Vw, v_b, Spart, out);
}

// Round 19
// 125.831 us; speedup vs baseline: 1.0899x; 1.0899x over previous
//
#include <hip/hip_runtime.h>
#include <hip/hip_bf16.h>

// PSAttentionBlock: B=16, C=KF=VF=128, H=W=128.
// out[b,f,h,w] = (v_w·x + v_b)[b,f,h,w] * S[b,h,w]
//   S[b,h,g] = sum_f softmax_{g<=h}( exp(Q[b,f]K[b,f]^T/sqrt(128)) )
//   Q/K from 1x1 conv with Weff[o,c] = qk_w[o,c]+qk_w[o,c+128]
// QK intermediate FP8 e4m3. K2 writes per-fgroup PARTIAL sums (plain stores,
// no atomics, no memset); K3 reduces the 16 partials in its prologue.
// == R17 configuration (best measured: 128.1 us) ==

using short8 = __attribute__((ext_vector_type(8))) short;
using f32x4  = __attribute__((ext_vector_type(4))) float;
typedef unsigned short u16;
typedef unsigned int   u32;
typedef unsigned char  u8;

#define NB 16
#define NC 128
#define NP 16384
#define TILES_QK 4
#define TILES_V 8
#define NFG 16                       // fgroups in K2 (8 planes each)
#define SCALE 0.08838834764831845f   // 128^-0.5

__device__ inline u16 f2bf(float f) {
  u32 u = __float_as_uint(f);
  return (u16)((u + 0x7FFFu + ((u >> 16) & 1u)) >> 16);   // RNE
}
__device__ inline u32 pk2(float a, float b) {             // 2xf32 -> packed bf16x2
  union { __hip_bfloat162 h; u32 u; } cv;
  cv.h = __float22bfloat162_rn(make_float2(a, b));
  return cv.u;
}
__device__ inline f32x4 fz4(){ f32x4 z; z[0]=0.f; z[1]=0.f; z[2]=0.f; z[3]=0.f; return z; }
__device__ inline long u2l(uint2 v){ union{uint2 u; long l;} c; c.u = v; return c.l; }
// row-swizzle for bf16 x-tiles: XOR 16B-chunk index within a 256B row
__device__ inline int kap(int r){ return ((r ^ (r >> 2)) & 15) << 4; }

// barrier that drains ONLY LDS (lgkm) — global loads/stores keep flying.
__device__ inline void barrier_lgkm() {
  __builtin_amdgcn_sched_barrier(0);
  asm volatile("s_waitcnt lgkmcnt(0)" ::: "memory");
  __builtin_amdgcn_s_barrier();
  __builtin_amdgcn_sched_barrier(0);
}

// ---------------- K0: weight prep -> bf16 ----------------
__global__ __launch_bounds__(256) void prep_w(
    const float* __restrict__ qk_w, const float* __restrict__ v_w,
    u16* __restrict__ Weff, u16* __restrict__ Vw) {
  const int i = blockIdx.x * 256 + threadIdx.x;           // 16384 threads
  #pragma unroll
  for (int r = 0; r < 2; ++r) {
    const int e = i * 2 + r;
    const int f = e >> 7, c = e & 127;
    Weff[e] = f2bf(qk_w[f * 256 + c] + qk_w[f * 256 + 128 + c]);
  }
  Vw[i] = f2bf(v_w[i]);
}

// staging helpers: [64 p][128 c] x-tile -> LDS transposed+swizzled bf16
__device__ inline void stage_issue(const float* __restrict__ xb, int tid,
                                   float4& r0, float4& r1, float4& r2, float4& r3) {
  const int c0 = (tid >> 4) * 4, p0 = (tid & 15) * 4;
  r0 = *(const float4*)(xb + (size_t)(c0 + 0) * NP + p0);
  r1 = *(const float4*)(xb + (size_t)(c0 + 1) * NP + p0);
  r2 = *(const float4*)(xb + (size_t)(c0 + 2) * NP + p0);
  r3 = *(const float4*)(xb + (size_t)(c0 + 3) * NP + p0);
}
__device__ inline void stage_write(u16* xs, int tid,
                                   float4 r0, float4 r1, float4 r2, float4 r3) {
  const int c0 = (tid >> 4) * 4, p0 = (tid & 15) * 4;
  const float* a0 = (const float*)&r0;
  const float* a1 = (const float*)&r1;
  const float* a2 = (const float*)&r2;
  const float* a3 = (const float*)&r3;
  #pragma unroll
  for (int j = 0; j < 4; ++j) {
    const int p = p0 + j;
    uint2 pk;
    pk.x = pk2(a0[j], a1[j]);
    pk.y = pk2(a2[j], a3[j]);
    *(uint2*)((char*)xs + p * 256 + ((c0 * 2) ^ kap(p))) = pk;
  }
}

// ---------------- K1: QK conv -> fp8 planes, coalesced stores ----------------
// grid (64 tilegroups of 4x64p, 16 b), 512 thr; wave wv owns f [wv*32, wv*32+32)
__global__ __launch_bounds__(512, 2) void qk_conv(
    const float* __restrict__ x, const u16* __restrict__ Weff,
    const float* __restrict__ qk_b, u8* __restrict__ QK) {
  __shared__ u16 xs[2][64 * 128];             // 2 x 16 KB
  __shared__ char rb[8][2048];                // 8 waves x 2 KB fp8 restage
  const int b = blockIdx.y, tg = blockIdx.x, tid = threadIdx.x;
  const int wv = tid >> 6, l = tid & 63, l15 = l & 15, lq = l >> 4;
  const float* xb = x + (size_t)b * NC * NP + tg * (64 * TILES_QK);

  short8 wf[4][2];                             // tile-invariant, L2-resident
  #pragma unroll
  for (int ks = 0; ks < 4; ++ks) {
    const int cc = ks * 32 + lq * 8;
    wf[ks][0] = *(const short8*)(Weff + (size_t)(wv * 32 + l15) * 128 + cc);
    wf[ks][1] = *(const short8*)(Weff + (size_t)(wv * 32 + 16 + l15) * 128 + cc);
  }
  const float bias0 = qk_b[wv * 32 + l15];
  const float bias1 = qk_b[wv * 32 + 16 + l15];

  float4 r0, r1, r2, r3;
  stage_issue(xb, tid, r0, r1, r2, r3);
  stage_write(xs[0], tid, r0, r1, r2, r3);

  for (int t = 0; t < TILES_QK; ++t) {
    if (t + 1 < TILES_QK) stage_issue(xb + (t + 1) * 64, tid, r0, r1, r2, r3);
    barrier_lgkm();

    const u16* cur = xs[t & 1];
    f32x4 acc[4][2];
    #pragma unroll
    for (int m = 0; m < 4; ++m) { acc[m][0] = fz4(); acc[m][1] = fz4(); }
    #pragma unroll
    for (int ks = 0; ks < 4; ++ks) {
      const int cc2 = (ks * 32 + lq * 8) * 2;
      #pragma unroll
      for (int m = 0; m < 4; ++m) {
        const int p = m * 16 + l15;
        short8 af = *(const short8*)((const char*)cur + p * 256 + (cc2 ^ kap(p)));
        acc[m][0] = __builtin_amdgcn_mfma_f32_16x16x32_bf16(af, wf[ks][0], acc[m][0], 0, 0, 0);
        acc[m][1] = __builtin_amdgcn_mfma_f32_16x16x32_bf16(af, wf[ks][1], acc[m][1], 0, 0, 0);
      }
    }

    if (t + 1 < TILES_QK) stage_write(xs[(t + 1) & 1], tid, r0, r1, r2, r3);

    // pack fp8 (RNE) into per-wave restage LDS ([32 f][64 p] fp8, 16B-granule
    // XOR by f&3), then 2 coalesced 16B stores (16 planes x 64B per op).
    const int pbase = tg * (64 * TILES_QK) + t * 64;
    char* rbw = rb[wv];
    #pragma unroll
    for (int n = 0; n < 2; ++n) {
      const int fl = n * 16 + l15;
      const float bias = n ? bias1 : bias0;
      #pragma unroll
      for (int m = 0; m < 4; ++m) {
        int pk4 = __builtin_amdgcn_cvt_pk_fp8_f32(acc[m][n][0] + bias,
                                                  acc[m][n][1] + bias, 0, false);
        pk4 = __builtin_amdgcn_cvt_pk_fp8_f32(acc[m][n][2] + bias,
                                              acc[m][n][3] + bias, pk4, true);
        *(int*)(rbw + fl * 64 + ((m ^ (fl & 3)) * 16) + lq * 4) = pk4;
      }
    }
    #pragma unroll
    for (int i = 0; i < 2; ++i) {
      const int r = i * 16 + (l >> 2);
      const int pg = l & 3, lg = pg ^ (r & 3);      // physical/logical granule
      uint4 v = *(const uint4*)(rbw + r * 64 + pg * 16);
      *(uint4*)((char*)QK + (((size_t)(b * 256 + wv * 32 + r)) << 14)
                + pbase + lg * 16) = v;
    }
  }
}

// ---------------- K2: fp8 scores + causal softmax -> Spart[fg][b] ------------
// grid (16 fgroups of 8, 16 b), 512 thr; wave wv owns rows h [wv*16, wv*16+16)
// Plain stores of the per-fgroup partial S (full coverage -> no init needed).
__global__ __launch_bounds__(512, 2) void scores_softmax(
    const u8* __restrict__ QK, float* __restrict__ Spart) {
  __shared__ u8 Ksm[2][16384];                // 2 x 16 KB fp8 K planes
  const int b = blockIdx.y, fg = blockIdx.x, tid = threadIdx.x;
  const int wv = tid >> 6, l = tid & 63, l15 = l & 15, lq = l >> 4;
  const int hbase = wv * 16;

  // staging: dest 16B-granule linear, src granule XOR'd by ((row>>1)&7) within
  // its 128B row -> LDS content lands pre-swizzled (same cache lines -> free)
  int srcoff[2];
  #pragma unroll
  for (int s = 0; s < 2; ++s) {
    const int a = s * 512 + tid;              // granule 0..1023
    const int g = a >> 3, gr = a & 7;         // row, granule-in-row
    srcoff[s] = ((a & ~7) | (gr ^ ((g >> 1) & 7))) * 16;
  }

  {
    const char* kp = (const char*)QK + (((size_t)(b * 256 + 128 + fg * 8)) << 14);
    #pragma unroll
    for (int s = 0; s < 2; ++s)
      *(uint4*)((char*)Ksm[0] + (s * 512 + tid) * 16) = *(const uint4*)(kp + srcoff[s]);
  }
  __syncthreads();

  float Sacc[8][4];
  #pragma unroll
  for (int n = 0; n < 8; ++n)
    #pragma unroll
    for (int r = 0; r < 4; ++r) Sacc[n][r] = 0.f;

  for (int fi = 0; fi < 8; ++fi) {
    const u8* kb = Ksm[fi & 1];
    const bool pf = (fi < 7);
    uint4 st0, st1;
    if (pf) {
      const char* kp = (const char*)QK + (((size_t)(b * 256 + 128 + fg * 8 + fi + 1)) << 14);
      st0 = *(const uint4*)(kp + srcoff[0]);
      st1 = *(const uint4*)(kp + srcoff[1]);
    }

    const char* Qp = (const char*)QK + (((size_t)(b * 256 + fg * 8 + fi)) << 14);
    f32x4 acc[8];
    #pragma unroll
    for (int n = 0; n < 8; ++n) acc[n] = fz4();
    #pragma unroll
    for (int ks = 0; ks < 4; ++ks) {
      const int hq = hbase + l15;
      uint2 aq = *(const uint2*)(Qp + hq * 128 + ks * 32 + lq * 8);  // linear Q
      const long a8 = u2l(aq);
      #pragma unroll
      for (int n = 0; n < 8; ++n) {
        const int g = n * 16 + l15;
        uint2 bq = *(const uint2*)((const char*)kb + g * 128
                                   + (((ks * 4 + lq) ^ (g & 14)) << 3));
        acc[n] = __builtin_amdgcn_mfma_f32_16x16x32_fp8_fp8(a8, u2l(bq), acc[n], 0, 0, 0);
      }
    }

    float part[4] = {0.f, 0.f, 0.f, 0.f};
    #pragma unroll
    for (int n = 0; n < 8; ++n)
      #pragma unroll
      for (int r = 0; r < 4; ++r) {
        const int h = hbase + lq * 4 + r;
        const int g = n * 16 + l15;
        float e = (g <= h) ? __expf(acc[n][r] * SCALE) : 0.f;   // faithful: no max-sub
        acc[n][r] = e;
        part[r] += e;
      }
    #pragma unroll
    for (int r = 0; r < 4; ++r) {
      part[r] += __shfl_xor(part[r], 1);
      part[r] += __shfl_xor(part[r], 2);
      part[r] += __shfl_xor(part[r], 4);
      part[r] += __shfl_xor(part[r], 8);
    }
    #pragma unroll
    for (int r = 0; r < 4; ++r) part[r] = 1.0f / part[r];
    #pragma unroll
    for (int n = 0; n < 8; ++n)
      #pragma unroll
      for (int r = 0; r < 4; ++r) Sacc[n][r] += acc[n][r] * part[r];

    if (pf) {
      char* kd = (char*)Ksm[(fi & 1) ^ 1];
      *(uint4*)(kd + (0 * 512 + tid) * 16) = st0;
      *(uint4*)(kd + (1 * 512 + tid) * 16) = st1;
    }
    __syncthreads();
  }

  // plain stores: this block covers ALL 16384 (h,g) of its partial plane
  float* Sp = Spart + ((size_t)(fg * NB + b)) * NP;
  #pragma unroll
  for (int n = 0; n < 8; ++n)
    #pragma unroll
    for (int r = 0; r < 4; ++r) {
      const int h = hbase + lq * 4 + r, g = n * 16 + l15;
      Sp[h * 128 + g] = Sacc[n][r];
    }
}

// ---------------- K3: V conv + S-partial reduce + scale -> out ---------------
__device__ inline void v_compute(const u16* cur, int l15, int lq,
                                 f32x4 acc[4], const short8 wf[4]) {
  #pragma unroll
  for (int m = 0; m < 4; ++m) acc[m] = fz4();
  #pragma unroll
  for (int ks = 0; ks < 4; ++ks) {
    const int cc2 = (ks * 32 + lq * 8) * 2;
    #pragma unroll
    for (int m = 0; m < 4; ++m) {
      const int p = m * 16 + l15;
      short8 af = *(const short8*)((const char*)cur + p * 256 + (cc2 ^ kap(p)));
      acc[m] = __builtin_amdgcn_mfma_f32_16x16x32_bf16(af, wf[ks], acc[m], 0, 0, 0);
    }
  }
}
__device__ inline void v_store(float* orow, const float* Ssm, int lq,
                               const f32x4 acc[4], int pbase, int ploc, float vb) {
  #pragma unroll
  for (int m = 0; m < 4; ++m) {
    const int o = m * 16 + lq * 4;
    float4 sv = *(const float4*)(Ssm + ploc + o);
    float4 oo;
    oo.x = (acc[m][0] + vb) * sv.x;
    oo.y = (acc[m][1] + vb) * sv.y;
    oo.z = (acc[m][2] + vb) * sv.z;
    oo.w = (acc[m][3] + vb) * sv.w;
    *(float4*)(orow + pbase + o) = oo;
  }
}

// grid (32 tilegroups, 16 b), 512 thr; wave wv owns f [wv*16, wv*16+16)
__global__ __launch_bounds__(512, 2) void v_conv_mul(
    const float* __restrict__ x, const u16* __restrict__ Vw,
    const float* __restrict__ v_b, const float* __restrict__ Spart,
    float* __restrict__ out) {
  __shared__ u16 xs[2][64 * 128];
  __shared__ float Ssm[512];                  // reduced S for this block's 512 p
  const int b = blockIdx.y, tg = blockIdx.x, tid = threadIdx.x;
  const int wv = tid >> 6, l = tid & 63, l15 = l & 15, lq = l >> 4;
  const float* xb = x + (size_t)b * NC * NP + tg * (64 * TILES_V);

  short8 wf[4];
  #pragma unroll
  for (int ks = 0; ks < 4; ++ks)
    wf[ks] = *(const short8*)(Vw + (size_t)(wv * 16 + l15) * 128 + ks * 32 + lq * 8);
  const int f = wv * 16 + l15;
  const float vb = v_b[f];
  float* orow = out + (size_t)(b * 128 + f) * NP;

  // prologue: reduce 16 S partials for this block's p range into LDS
  {
    const size_t poff = (size_t)b * NP + tg * 512 + tid;
    float s = 0.f;
    #pragma unroll
    for (int q = 0; q < NFG; ++q) s += Spart[(size_t)q * NB * NP + poff];
    Ssm[tid] = s;
  }

  float4 A0, A1, A2, A3, B0, B1, B2, B3;
  stage_issue(xb, tid, A0, A1, A2, A3);
  stage_write(xs[0], tid, A0, A1, A2, A3);
  stage_issue(xb + 64, tid, B0, B1, B2, B3);

  f32x4 acc[4];
  #pragma unroll
  for (int tp = 0; tp < TILES_V; tp += 2) {
    barrier_lgkm();
    if (tp + 2 < TILES_V) stage_issue(xb + (tp + 2) * 64, tid, A0, A1, A2, A3);
    v_compute(xs[0], l15, lq, acc, wf);
    if (tp + 1 < TILES_V) stage_write(xs[1], tid, B0, B1, B2, B3);
    v_store(orow, Ssm, lq, acc, tg * (64 * TILES_V) + tp * 64, tp * 64, vb);
    barrier_lgkm();
    if (tp + 3 < TILES_V) stage_issue(xb + (tp + 3) * 64, tid, B0, B1, B2, B3);
    v_compute(xs[1], l15, lq, acc, wf);
    if (tp + 2 < TILES_V) stage_write(xs[0], tid, A0, A1, A2, A3);
    v_store(orow, Ssm, lq, acc, tg * (64 * TILES_V) + (tp + 1) * 64, (tp + 1) * 64, vb);
  }
}

extern "C" void kernel_launch(void* const* d_in, const int* in_sizes, int n_in,
                              void* d_out, int out_size, void* d_ws, size_t ws_size,
                              hipStream_t stream) {
  const float* x    = (const float*)d_in[0];
  const float* qk_w = (const float*)d_in[1];
  const float* qk_b = (const float*)d_in[2];
  const float* v_w  = (const float*)d_in[3];
  const float* v_b  = (const float*)d_in[4];
  float* out = (float*)d_out;

  char* ws = (char*)d_ws;
  u8*    QK    = (u8*)ws;                                  // 67,108,864 B (fp8)
  float* Spart = (float*)(ws + (size_t)67108864);          // 16,777,216 B
  u16*   Weff  = (u16*)(ws + (size_t)67108864 + 16777216); //     65,536 B
  u16*   Vw    = (u16*)(ws + (size_t)67108864 + 16777216 + 65536);  // 32,768 B

  prep_w<<<64, 256, 0, stream>>>(qk_w, v_w, Weff, Vw);
  qk_conv<<<dim3(64, 16), 512, 0, stream>>>(x, Weff, qk_b, QK);
  scores_softmax<<<dim3(16, 16), 512, 0, stream>>>(QK, Spart);
  v_conv_mul<<<dim3(32, 16), 512, 0, stream>>>(x, Vw, v_b, Spart, out);
}